// Round 1
// baseline (1382.693 us; speedup 1.0000x reference)
//
#include <hip/hip_runtime.h>
#include <math.h>

#define NN 20000
#define NE 320000
#define F 128
#define NLAYER 3
#define CATW 2048   // F * 16

// ---------------- utility kernels ----------------

__global__ void zero_ints_kernel(int* __restrict__ a, int* __restrict__ b, int n) {
    int i = blockIdx.x * blockDim.x + threadIdx.x;
    if (i < n) { a[i] = 0; b[i] = 0; }
}

__global__ void hist_kernel(const int* __restrict__ dst, int* __restrict__ cnt, int e) {
    int i = blockIdx.x * blockDim.x + threadIdx.x;
    if (i < e) atomicAdd(&cnt[dst[i]], 1);
}

// single-workgroup exclusive scan over n counters (n <= 1024*chunk)
__global__ void scan_kernel(const int* __restrict__ cnt, int* __restrict__ off, int n) {
    __shared__ int sums[1024];
    int tid = threadIdx.x;
    int chunk = (n + 1023) >> 10;
    int b0 = tid * chunk;
    int b1 = min(b0 + chunk, n);
    int s = 0;
    for (int i = b0; i < b1; ++i) s += cnt[i];
    sums[tid] = s;
    __syncthreads();
    for (int d = 1; d < 1024; d <<= 1) {
        int v = (tid >= d) ? sums[tid - d] : 0;
        __syncthreads();
        sums[tid] += v;
        __syncthreads();
    }
    int pre = (tid == 0) ? 0 : sums[tid - 1];
    for (int i = b0; i < b1; ++i) { off[i] = pre; pre += cnt[i]; }
    if (tid == 1023) off[n] = pre;
}

__global__ void scatter_kernel(const int* __restrict__ src, const int* __restrict__ dst,
                               const int* __restrict__ off, int* __restrict__ cur,
                               int* __restrict__ csr, int e) {
    int i = blockIdx.x * blockDim.x + threadIdx.x;
    if (i < e) {
        int d = dst[i];
        int p = atomicAdd(&cur[d], 1);
        csr[off[d] + p] = src[i];
    }
}

__global__ void scaler_kernel(const int* __restrict__ cnt, float* __restrict__ amp,
                              float* __restrict__ att, float avg_log, int n) {
    int i = blockIdx.x * blockDim.x + threadIdx.x;
    if (i < n) {
        float deg = fmaxf((float)cnt[i], 1.0f);
        float ld = logf(deg + 1.0f);
        amp[i] = ld / avg_log;
        att[i] = avg_log / ld;
    }
}

__global__ void catx_kernel(const float* __restrict__ x, float* __restrict__ cat) {
    int i = blockIdx.x * blockDim.x + threadIdx.x;  // over NN*F
    if (i < NN * F) {
        int node = i / F, d = i % F;
        cat[(size_t)node * CATW + d] = x[i];
    }
}

// ---------------- aggregation (one block of 128 threads per node) ----------------

__global__ void agg_kernel(const float* __restrict__ bbuf, const float* __restrict__ cbuf,
                           const int* __restrict__ off, const int* __restrict__ csr,
                           const float* __restrict__ amp, const float* __restrict__ att,
                           float* __restrict__ cat) {
    int i = blockIdx.x;      // node
    int d = threadIdx.x;     // feature dim
    int o0 = off[i], o1 = off[i + 1];
    float sum = 0.f, ssq = 0.f, mn = 1e30f, mx = -1e30f;
    for (int j = o0; j < o1; ++j) {
        int s = csr[j];
        float v = bbuf[(size_t)s * F + d];
        sum += v; ssq += v * v;
        mn = fminf(mn, v); mx = fmaxf(mx, v);
    }
    int degi = o1 - o0;
    float m_mean, m_s, m_std, m_mn, m_mx;
    if (degi == 0) {
        m_s = 0.f; m_mean = 0.f; m_std = sqrtf(1e-5f); m_mn = 0.f; m_mx = 0.f;
    } else {
        float cv = cbuf[(size_t)i * F + d];
        float degf = (float)degi;
        m_s = degf * cv + sum;
        m_mean = m_s / degf;
        float msq = cv * cv + (2.f * cv * sum + ssq) / degf;
        float var = msq - m_mean * m_mean;
        m_std = sqrtf(fmaxf(var, 0.f) + 1e-5f);
        m_mn = cv + mn;
        m_mx = cv + mx;
    }
    float a = amp[i], t = att[i];
    float* row = cat + (size_t)i * CATW + F;
    row[0 * F + d] = m_mean;
    row[1 * F + d] = m_s;
    row[2 * F + d] = m_std;
    row[3 * F + d] = m_mn;
    row[4 * F + d] = m_mx;
    row[640 + 0 * F + d] = m_mean * a;
    row[640 + 1 * F + d] = m_s * a;
    row[640 + 2 * F + d] = m_std * a;
    row[640 + 3 * F + d] = m_mn * a;
    row[640 + 4 * F + d] = m_mx * a;
    row[1280 + 0 * F + d] = m_mean * t;
    row[1280 + 1 * F + d] = m_s * t;
    row[1280 + 2 * F + d] = m_std * t;
    row[1280 + 3 * F + d] = m_mn * t;
    row[1280 + 4 * F + d] = m_mx * t;
}

// ---------------- generic fp32 GEMM: C[n,128] = A[n,K] @ B[K,128] (+bias)(+relu) ----------------
// 64x128 block tile, 256 threads, 4x8 microtile per thread, K-chunks of 32.

template <bool BIAS, bool RELU>
__global__ __launch_bounds__(256) void gemm_kernel(
    const float* __restrict__ A, int lda, const float* __restrict__ B,
    const float* __restrict__ bias, float* __restrict__ C, int ldc,
    int nrows, int K) {
    __shared__ float As[64][33];
    __shared__ float Bs[32][128];
    int tid = threadIdx.x;
    int row0 = blockIdx.x * 64;
    int colg = tid & 15;   // 16 col groups x 8 cols
    int rowg = tid >> 4;   // 16 row groups x 4 rows
    int col = colg * 8;
    int trow = rowg * 4;

    float acc[4][8];
#pragma unroll
    for (int r = 0; r < 4; ++r)
#pragma unroll
        for (int c = 0; c < 8; ++c) acc[r][c] = 0.f;

    for (int k0 = 0; k0 < K; k0 += 32) {
        {   // A tile 64x32
            int kk = tid & 31;
            int rbase = tid >> 5;  // 0..7
#pragma unroll
            for (int p = 0; p < 8; ++p) {
                int r = rbase + p * 8;
                int grow = row0 + r;
                As[r][kk] = (grow < nrows) ? A[(size_t)grow * lda + k0 + kk] : 0.f;
            }
        }
        {   // B tile 32x128
            int c = tid & 127;
            int kb = tid >> 7;  // 0..1
#pragma unroll
            for (int p = 0; p < 16; ++p) {
                int kr = kb + p * 2;
                Bs[kr][c] = B[(size_t)(k0 + kr) * F + c];
            }
        }
        __syncthreads();
#pragma unroll
        for (int kk = 0; kk < 32; ++kk) {
            float a[4];
#pragma unroll
            for (int r = 0; r < 4; ++r) a[r] = As[trow + r][kk];
            float4 b0 = *(const float4*)&Bs[kk][col];
            float4 b1 = *(const float4*)&Bs[kk][col + 4];
            float b[8] = {b0.x, b0.y, b0.z, b0.w, b1.x, b1.y, b1.z, b1.w};
#pragma unroll
            for (int r = 0; r < 4; ++r)
#pragma unroll
                for (int c = 0; c < 8; ++c) acc[r][c] += a[r] * b[c];
        }
        __syncthreads();
    }

#pragma unroll
    for (int r = 0; r < 4; ++r) {
        int grow = row0 + trow + r;
        if (grow < nrows) {
            float v[8];
#pragma unroll
            for (int c = 0; c < 8; ++c) {
                float t = acc[r][c];
                if (BIAS) t += bias[col + c];
                if (RELU) t = fmaxf(t, 0.f);
                v[c] = t;
            }
            float4* out = (float4*)&C[(size_t)grow * ldc + col];
            out[0] = make_float4(v[0], v[1], v[2], v[3]);
            out[1] = make_float4(v[4], v[5], v[6], v[7]);
        }
    }
}

// ---------------- final output: y[i] = x[i,:] . Wout + bout ----------------

__global__ void out_kernel(const float* __restrict__ x, const float* __restrict__ Wout,
                           const float* __restrict__ bout, float* __restrict__ y) {
    int gid = blockIdx.x * blockDim.x + threadIdx.x;
    int wid = gid >> 6;
    int lane = threadIdx.x & 63;
    if (wid >= NN) return;
    const float* xr = x + (size_t)wid * F;
    float v = xr[lane] * Wout[lane] + xr[lane + 64] * Wout[lane + 64];
#pragma unroll
    for (int o = 32; o > 0; o >>= 1) v += __shfl_down(v, o, 64);
    if (lane == 0) y[wid] = v + bout[0];
}

// ---------------- host ----------------

extern "C" void kernel_launch(void* const* d_in, const int* in_sizes, int n_in,
                              void* d_out, int out_size, void* d_ws, size_t ws_size,
                              hipStream_t stream) {
    const float* x_in   = (const float*)d_in[0];
    const int*   ei     = (const int*)d_in[1];
    const float* W_pre  = (const float*)d_in[2];
    const float* b_pre  = (const float*)d_in[3];
    const float* W_post = (const float*)d_in[4];
    const float* b_post = (const float*)d_in[5];
    const float* W_lin  = (const float*)d_in[6];
    const float* b_lin  = (const float*)d_in[7];
    const float* W_out  = (const float*)d_in[8];
    const float* b_out  = (const float*)d_in[9];

    const int* src = ei;
    const int* dst = ei + NE;

    double s = 0.0;
    for (int i = 0; i < 33; ++i) s += log((double)(i + 1));
    float avg_log = (float)(s / 33.0);

    char* ws = (char*)d_ws;
    size_t p = 0;
    auto alloc = [&](size_t bytes) { void* r = ws + p; p += (bytes + 255) & ~(size_t)255; return r; };
    float* cat  = (float*)alloc((size_t)NN * CATW * 4);
    float* bbuf = (float*)alloc((size_t)NN * F * 4);
    float* cbuf = (float*)alloc((size_t)NN * F * 4);
    float* obuf = (float*)alloc((size_t)NN * F * 4);
    float* xbuf = (float*)alloc((size_t)NN * F * 4);
    int*   cnt  = (int*)alloc((size_t)NN * 4);
    int*   offs = (int*)alloc((size_t)(NN + 1) * 4);
    int*   cur  = (int*)alloc((size_t)NN * 4);
    int*   csr  = (int*)alloc((size_t)NE * 4);
    float* amp  = (float*)alloc((size_t)NN * 4);
    float* att  = (float*)alloc((size_t)NN * 4);
    (void)ws_size;

    // graph structure (recomputed every call; deterministic work)
    zero_ints_kernel<<<(NN + 255) / 256, 256, 0, stream>>>(cnt, cur, NN);
    hist_kernel<<<(NE + 255) / 256, 256, 0, stream>>>(dst, cnt, NE);
    scan_kernel<<<1, 1024, 0, stream>>>(cnt, offs, NN);
    scaler_kernel<<<(NN + 255) / 256, 256, 0, stream>>>(cnt, amp, att, avg_log, NN);
    scatter_kernel<<<(NE + 255) / 256, 256, 0, stream>>>(src, dst, offs, cur, csr, NE);

    int gemm_grid = (NN + 63) / 64;
    const float* xcur = x_in;
    for (int l = 0; l < NLAYER; ++l) {
        const float* Wtop = W_pre + (size_t)l * 2 * F * F;
        const float* Wbot = Wtop + (size_t)F * F;
        // c = x @ Wtop + b_pre ; b = x @ Wbot
        gemm_kernel<true, false><<<gemm_grid, 256, 0, stream>>>(
            xcur, F, Wtop, b_pre + (size_t)l * F, cbuf, F, NN, F);
        gemm_kernel<false, false><<<gemm_grid, 256, 0, stream>>>(
            xcur, F, Wbot, nullptr, bbuf, F, NN, F);
        // cat[:,0:128] = x ; cat[:,128:2048] = scaled aggregates
        catx_kernel<<<(NN * F + 255) / 256, 256, 0, stream>>>(xcur, cat);
        agg_kernel<<<NN, F, 0, stream>>>(bbuf, cbuf, offs, csr, amp, att, cat);
        // out = cat @ W_post + b_post
        gemm_kernel<true, false><<<gemm_grid, 256, 0, stream>>>(
            cat, CATW, W_post + (size_t)l * CATW * F, b_post + (size_t)l * F, obuf, F, NN, CATW);
        // x = relu(out @ W_lin + b_lin)
        gemm_kernel<true, true><<<gemm_grid, 256, 0, stream>>>(
            obuf, F, W_lin + (size_t)l * F * F, b_lin + (size_t)l * F, xbuf, F, NN, F);
        xcur = xbuf;
    }
    out_kernel<<<(NN * 64 + 255) / 256, 256, 0, stream>>>(xcur, W_out, b_out, (float*)d_out);
}

// Round 2
// 374.154 us; speedup vs baseline: 3.6955x; 3.6955x over previous
//
#include <hip/hip_runtime.h>
#include <math.h>

#define NN 20000
#define NE 320000
#define F 128
#define NLAYER 3
#define MPAD 20032          // 313 * 64
#define CATW 2048

typedef unsigned int u32;
typedef unsigned short u16;
typedef __attribute__((ext_vector_type(8))) short bf16x8;
typedef __attribute__((ext_vector_type(4))) float f32x4;

__device__ __forceinline__ u16 f2bf(float f) {
    union { float f; u32 u; } x{f};
    u32 r = x.u + 0x7FFFu + ((x.u >> 16) & 1u);
    return (u16)(r >> 16);
}
__device__ __forceinline__ float bflo(u32 u) { return __uint_as_float(u << 16); }
__device__ __forceinline__ float bfhi(u32 u) { return __uint_as_float(u & 0xFFFF0000u); }

__device__ __forceinline__ void gload16(const u16* g, u16* l) {
    __builtin_amdgcn_global_load_lds(
        (const __attribute__((address_space(1))) void*)g,
        (__attribute__((address_space(3))) void*)l, 16, 0, 0);
}

// ---------------- setup kernels ----------------

__global__ void zero_ints_kernel(int* __restrict__ a, int* __restrict__ b, int n) {
    int i = blockIdx.x * blockDim.x + threadIdx.x;
    if (i < n) { a[i] = 0; b[i] = 0; }
}

__global__ void hist_kernel(const int* __restrict__ dst, int* __restrict__ cnt, int e) {
    int i = blockIdx.x * blockDim.x + threadIdx.x;
    if (i < e) atomicAdd(&cnt[dst[i]], 1);
}

__global__ void scan_kernel(const int* __restrict__ cnt, int* __restrict__ off, int n) {
    __shared__ int sums[1024];
    int tid = threadIdx.x;
    int chunk = (n + 1023) >> 10;
    int b0 = tid * chunk;
    int b1 = min(b0 + chunk, n);
    int s = 0;
    for (int i = b0; i < b1; ++i) s += cnt[i];
    sums[tid] = s;
    __syncthreads();
    for (int d = 1; d < 1024; d <<= 1) {
        int v = (tid >= d) ? sums[tid - d] : 0;
        __syncthreads();
        sums[tid] += v;
        __syncthreads();
    }
    int pre = (tid == 0) ? 0 : sums[tid - 1];
    for (int i = b0; i < b1; ++i) { off[i] = pre; pre += cnt[i]; }
    if (tid == 1023) off[n] = pre;
}

__global__ void scatter_kernel(const int* __restrict__ src, const int* __restrict__ dst,
                               const int* __restrict__ off, int* __restrict__ cur,
                               int* __restrict__ csr, int e) {
    int i = blockIdx.x * blockDim.x + threadIdx.x;
    if (i < e) {
        int d = dst[i];
        int p = atomicAdd(&cur[d], 1);
        csr[off[d] + p] = src[i];
    }
}

// ---------------- weight / input prep ----------------

__global__ void xprep_kernel(const float* __restrict__ x, u16* __restrict__ xbuf,
                             u16* __restrict__ cat) {
    int i = blockIdx.x * 256 + threadIdx.x;
    if (i < NN * F) {
        u16 h = f2bf(x[i]);
        xbuf[i] = h;
        cat[(size_t)(i >> 7) * CATW + (i & 127)] = h;
    }
}

// W_preT[l][c][k], c in [0,256): c<128 -> Wtop[k][c], else Wbot[k][c-128]
__global__ void wpreT_kernel(const float* __restrict__ W_pre, u16* __restrict__ dst) {
    int l = blockIdx.y;
    int i = blockIdx.x * 256 + threadIdx.x;   // 32768 per layer
    if (i < 256 * 128) {
        int c = i >> 7, k = i & 127;
        int si = (c < 128) ? (k * 128 + c) : ((k + 128) * 128 + (c - 128));
        dst[l * 32768 + i] = f2bf(W_pre[l * 32768 + si]);
    }
}

__global__ void wlinT_kernel(const float* __restrict__ W_lin, u16* __restrict__ dst) {
    int l = blockIdx.y;
    int i = blockIdx.x * 256 + threadIdx.x;   // 16384 per layer
    if (i < 128 * 128) {
        int c = i >> 7, k = i & 127;
        dst[l * 16384 + i] = f2bf(W_lin[l * 16384 + k * 128 + c]);
    }
}

__global__ void wpost_kernel(const float* __restrict__ W_post, u16* __restrict__ dst) {
    int i = blockIdx.x * 256 + threadIdx.x;   // 3*2048*128
    if (i < 3 * 2048 * 128) dst[i] = f2bf(W_post[i]);
}

// biaspre[l][0:128]=b_pre, [128:256]=0 ; bcomb[l][j] = b_post@W_lin + b_lin
__global__ void bias_kernel(const float* __restrict__ b_pre, const float* __restrict__ b_post,
                            const float* __restrict__ b_lin, const float* __restrict__ W_lin,
                            float* __restrict__ biaspre, float* __restrict__ bcomb) {
    int l = blockIdx.x, t = threadIdx.x;
    if (t < 128) {
        float s = b_lin[l * 128 + t];
        for (int c = 0; c < 128; ++c) s += b_post[l * 128 + c] * W_lin[l * 16384 + c * 128 + t];
        bcomb[l * 128 + t] = s;
        biaspre[l * 256 + t] = b_pre[l * 128 + t];
    } else {
        biaspre[l * 256 + t] = 0.f;
    }
}

// ---------------- aggregation: one wave per node, 2 features per lane ----------------

__global__ void agg_kernel(const u16* __restrict__ preout, const int* __restrict__ off,
                           const int* __restrict__ csr, u16* __restrict__ cat, float avg_log) {
    int gid = blockIdx.x * blockDim.x + threadIdx.x;
    int node = gid >> 6, lane = threadIdx.x & 63;
    if (node >= NN) return;
    int o0 = off[node], o1 = off[node + 1];
    const u32* bp = (const u32*)preout;           // row = 128 uints
    float s0 = 0, s1 = 0, q0 = 0, q1 = 0;
    float mn0 = 1e30f, mn1 = 1e30f, mx0 = -1e30f, mx1 = -1e30f;
    for (int j = o0; j < o1; ++j) {
        int sr = csr[j];
        u32 u = bp[(size_t)sr * 128 + 64 + lane]; // b-half (cols 128:256)
        float v0 = bflo(u), v1 = bfhi(u);
        s0 += v0; q0 += v0 * v0; mn0 = fminf(mn0, v0); mx0 = fmaxf(mx0, v0);
        s1 += v1; q1 += v1 * v1; mn1 = fminf(mn1, v1); mx1 = fmaxf(mx1, v1);
    }
    int degi = o1 - o0;
    float mean0, mean1, sum0, sum1, std0, std1, lo0, lo1, hi0, hi1;
    if (degi == 0) {
        sum0 = sum1 = 0.f; mean0 = mean1 = 0.f;
        std0 = std1 = sqrtf(1e-5f);
        lo0 = lo1 = hi0 = hi1 = 0.f;
    } else {
        u32 uc = bp[(size_t)node * 128 + lane];   // c-half (cols 0:128)
        float c0 = bflo(uc), c1 = bfhi(uc), dg = (float)degi;
        sum0 = dg * c0 + s0; mean0 = sum0 / dg;
        sum1 = dg * c1 + s1; mean1 = sum1 / dg;
        float msq0 = c0 * c0 + (2.f * c0 * s0 + q0) / dg;
        float msq1 = c1 * c1 + (2.f * c1 * s1 + q1) / dg;
        std0 = sqrtf(fmaxf(msq0 - mean0 * mean0, 0.f) + 1e-5f);
        std1 = sqrtf(fmaxf(msq1 - mean1 * mean1, 0.f) + 1e-5f);
        lo0 = c0 + mn0; lo1 = c1 + mn1; hi0 = c0 + mx0; hi1 = c1 + mx1;
    }
    float dgc = fmaxf((float)degi, 1.f);
    float ld = logf(dgc + 1.f);
    float amp = ld / avg_log, att = avg_log / ld;
    u32* cr = (u32*)cat + (size_t)node * (CATW / 2) + 64 + lane;
    float f0[5] = {mean0, sum0, std0, lo0, hi0};
    float f1[5] = {mean1, sum1, std1, lo1, hi1};
#pragma unroll
    for (int a = 0; a < 5; ++a) {
        cr[a * 64]       = (u32)f2bf(f0[a])       | ((u32)f2bf(f1[a]) << 16);
        cr[320 + a * 64] = (u32)f2bf(f0[a] * amp) | ((u32)f2bf(f1[a] * amp) << 16);
        cr[640 + a * 64] = (u32)f2bf(f0[a] * att) | ((u32)f2bf(f1[a] * att) << 16);
    }
}

// ---------------- bf16 MFMA GEMM: C[M,NC] = A[M,K] @ Bt[NC,K]^T ----------------
// tile 64 rows x 128 cols, 256 threads (4 waves), wave = 32x64 (2x4 16x16 frags)
// LDS swizzle: 16B slot ^= (row>>1)&3 (pre-swizzled global source, swizzled ds_read)

template <bool BIAS, bool RELU, bool DUAL>
__global__ __launch_bounds__(256) void mfma_gemm(
    const u16* __restrict__ A, int lda,
    const u16* __restrict__ Bt, int K,
    const float* __restrict__ bias,
    u16* __restrict__ C, int ldc,
    u16* __restrict__ C2, int ldc2,
    int Mreal) {
    __shared__ u16 As[64 * 32];
    __shared__ u16 Bs[128 * 32];
    int tid = threadIdx.x;
    int w = tid >> 6, lane = tid & 63;
    int row0 = blockIdx.x * 64, col0 = blockIdx.y * 128;

    // staging (linear LDS dest; source pre-swizzled)
    int arow = tid >> 2, asl = tid & 3;
    const u16* agp = A + (size_t)(row0 + arow) * lda + ((asl ^ ((arow >> 1) & 3)) << 3);
    u16* alds = As + w * 512;
    int br0 = tid >> 2;
    int br1 = 64 + (tid >> 2);
    const u16* bgp0 = Bt + (size_t)(col0 + br0) * K + (((tid & 3) ^ ((br0 >> 1) & 3)) << 3);
    const u16* bgp1 = Bt + (size_t)(col0 + br1) * K + (((tid & 3) ^ ((br1 >> 1) & 3)) << 3);
    u16* blds0 = Bs + w * 512;
    u16* blds1 = Bs + 2048 + w * 512;

    f32x4 acc[2][4];
#pragma unroll
    for (int m = 0; m < 2; ++m)
#pragma unroll
        for (int n = 0; n < 4; ++n) acc[m][n] = (f32x4){0.f, 0.f, 0.f, 0.f};

    int s = lane >> 4, r = lane & 15;
    int wr = (w >> 1) * 32, wc = (w & 1) * 64;

    for (int k0 = 0; k0 < K; k0 += 32) {
        gload16(agp + k0, alds);
        gload16(bgp0 + k0, blds0);
        gload16(bgp1 + k0, blds1);
        __syncthreads();
        bf16x8 a[2], b[4];
#pragma unroll
        for (int m = 0; m < 2; ++m) {
            int row = wr + m * 16 + r;
            a[m] = *(const bf16x8*)&As[row * 32 + ((s ^ ((row >> 1) & 3)) << 3)];
        }
#pragma unroll
        for (int n = 0; n < 4; ++n) {
            int col = wc + n * 16 + r;
            b[n] = *(const bf16x8*)&Bs[col * 32 + ((s ^ ((col >> 1) & 3)) << 3)];
        }
#pragma unroll
        for (int m = 0; m < 2; ++m)
#pragma unroll
            for (int n = 0; n < 4; ++n)
                acc[m][n] = __builtin_amdgcn_mfma_f32_16x16x32_bf16(a[m], b[n], acc[m][n], 0, 0, 0);
        __syncthreads();
    }

#pragma unroll
    for (int m = 0; m < 2; ++m) {
#pragma unroll
        for (int n = 0; n < 4; ++n) {
            int gcol = col0 + wc + n * 16 + r;
            float bs = BIAS ? bias[gcol] : 0.f;
#pragma unroll
            for (int j = 0; j < 4; ++j) {
                int grow = row0 + wr + m * 16 + s * 4 + j;
                if (grow < Mreal) {
                    float v = acc[m][n][j] + bs;
                    if (RELU) v = fmaxf(v, 0.f);
                    u16 h = f2bf(v);
                    C[(size_t)grow * ldc + gcol] = h;
                    if (DUAL) C2[(size_t)grow * ldc2 + gcol] = h;
                }
            }
        }
    }
}

// ---------------- final output ----------------

__global__ void out_kernel(const u16* __restrict__ x, const float* __restrict__ Wout,
                           const float* __restrict__ bout, float* __restrict__ y) {
    int gid = blockIdx.x * blockDim.x + threadIdx.x;
    int wid = gid >> 6, lane = threadIdx.x & 63;
    if (wid >= NN) return;
    u32 u = *(const u32*)&x[(size_t)wid * F + 2 * lane];
    float v = bflo(u) * Wout[2 * lane] + bfhi(u) * Wout[2 * lane + 1];
#pragma unroll
    for (int o = 32; o > 0; o >>= 1) v += __shfl_down(v, o, 64);
    if (lane == 0) y[wid] = v + bout[0];
}

// ---------------- host ----------------

extern "C" void kernel_launch(void* const* d_in, const int* in_sizes, int n_in,
                              void* d_out, int out_size, void* d_ws, size_t ws_size,
                              hipStream_t stream) {
    const float* x_in   = (const float*)d_in[0];
    const int*   ei     = (const int*)d_in[1];
    const float* W_pre  = (const float*)d_in[2];
    const float* b_pre  = (const float*)d_in[3];
    const float* W_post = (const float*)d_in[4];
    const float* b_post = (const float*)d_in[5];
    const float* W_lin  = (const float*)d_in[6];
    const float* b_lin  = (const float*)d_in[7];
    const float* W_out  = (const float*)d_in[8];
    const float* b_out  = (const float*)d_in[9];

    const int* src = ei;
    const int* dst = ei + NE;

    double sl = 0.0;
    for (int i = 0; i < 33; ++i) sl += log((double)(i + 1));
    float avg_log = (float)(sl / 33.0);

    char* ws = (char*)d_ws;
    size_t p = 0;
    auto alloc = [&](size_t bytes) { void* r = ws + p; p += (bytes + 255) & ~(size_t)255; return r; };
    u16*   cat     = (u16*)alloc((size_t)MPAD * CATW * 2);
    u16*   xbuf    = (u16*)alloc((size_t)MPAD * F * 2);
    u16*   preout  = (u16*)alloc((size_t)MPAD * 256 * 2);
    u16*   WpreT   = (u16*)alloc((size_t)3 * 256 * 128 * 2);
    u16*   Wpostb  = (u16*)alloc((size_t)3 * 2048 * 128 * 2);
    u16*   WlinT   = (u16*)alloc((size_t)3 * 128 * 128 * 2);
    u16*   Btcomb  = (u16*)alloc((size_t)3 * 128 * 2048 * 2);
    float* biaspre = (float*)alloc((size_t)3 * 256 * 4);
    float* bcomb   = (float*)alloc((size_t)3 * 128 * 4);
    int*   cnt     = (int*)alloc((size_t)NN * 4);
    int*   offs    = (int*)alloc((size_t)(NN + 1) * 4);
    int*   cur     = (int*)alloc((size_t)NN * 4);
    int*   csr     = (int*)alloc((size_t)NE * 4);
    (void)ws_size;

    // input / weight prep
    xprep_kernel<<<(NN * F + 255) / 256, 256, 0, stream>>>(x_in, xbuf, cat);
    wpreT_kernel<<<dim3(128, 3), 256, 0, stream>>>(W_pre, WpreT);
    wlinT_kernel<<<dim3(64, 3), 256, 0, stream>>>(W_lin, WlinT);
    wpost_kernel<<<3072, 256, 0, stream>>>(W_post, Wpostb);
    bias_kernel<<<3, 256, 0, stream>>>(b_pre, b_post, b_lin, W_lin, biaspre, bcomb);

    // graph structure
    zero_ints_kernel<<<(NN + 255) / 256, 256, 0, stream>>>(cnt, cur, NN);
    hist_kernel<<<(NE + 255) / 256, 256, 0, stream>>>(dst, cnt, NE);
    scan_kernel<<<1, 1024, 0, stream>>>(cnt, offs, NN);
    scatter_kernel<<<(NE + 255) / 256, 256, 0, stream>>>(src, dst, offs, cur, csr, NE);

    // Btcomb[l] = W_lin^T @ W_post^T  ([128 x 2048], = (W_post@W_lin)^T)
    for (int l = 0; l < NLAYER; ++l) {
        mfma_gemm<false, false, false><<<dim3(2, 16), 256, 0, stream>>>(
            WlinT + (size_t)l * 16384, 128, Wpostb + (size_t)l * 262144, 128,
            nullptr, Btcomb + (size_t)l * 262144, 2048, nullptr, 0, 128);
    }

    for (int l = 0; l < NLAYER; ++l) {
        // preout = x @ [Wtop|Wbot] + [b_pre|0]   -> [M,256] bf16
        mfma_gemm<true, false, false><<<dim3(313, 2), 256, 0, stream>>>(
            xbuf, F, WpreT + (size_t)l * 32768, 128,
            biaspre + (size_t)l * 256, preout, 256, nullptr, 0, NN);
        // aggregates -> cat[:,128:2048]
        agg_kernel<<<5000, 256, 0, stream>>>(preout, offs, csr, cat, avg_log);
        // x = relu(cat @ Wcomb + bcomb); dual-write xbuf and cat[:,0:128]
        mfma_gemm<true, true, true><<<dim3(313, 1), 256, 0, stream>>>(
            cat, CATW, Btcomb + (size_t)l * 262144, CATW,
            bcomb + (size_t)l * 128, xbuf, F, cat, CATW, NN);
    }

    out_kernel<<<5000, 256, 0, stream>>>(xbuf, W_out, b_out, (float*)d_out);
}

// Round 3
// 263.124 us; speedup vs baseline: 5.2549x; 1.4220x over previous
//
#include <hip/hip_runtime.h>
#include <math.h>

#define NN 20000
#define NE 320000
#define F 128
#define NLAYER 3
#define MPAD 20032          // 313 * 64
#define CATW 768            // [x | mean sum std min max]

typedef unsigned int u32;
typedef unsigned short u16;
typedef __attribute__((ext_vector_type(8))) short bf16x8;
typedef __attribute__((ext_vector_type(4))) float f32x4;

__device__ __forceinline__ u16 f2bf(float f) {
    union { float f; u32 u; } x{f};
    u32 r = x.u + 0x7FFFu + ((x.u >> 16) & 1u);
    return (u16)(r >> 16);
}
__device__ __forceinline__ float bflo(u32 u) { return __uint_as_float(u << 16); }
__device__ __forceinline__ float bfhi(u32 u) { return __uint_as_float(u & 0xFFFF0000u); }

__device__ __forceinline__ void gload16(const u16* g, u16* l) {
    __builtin_amdgcn_global_load_lds(
        (const __attribute__((address_space(1))) void*)g,
        (__attribute__((address_space(3))) void*)l, 16, 0, 0);
}

// ---------------- setup kernels ----------------

__global__ void zero_ints_kernel(int* __restrict__ a, int* __restrict__ b, int n) {
    int i = blockIdx.x * blockDim.x + threadIdx.x;
    if (i < n) { a[i] = 0; b[i] = 0; }
}

__global__ void hist_kernel(const int* __restrict__ dst, int* __restrict__ cnt, int e) {
    int i = blockIdx.x * blockDim.x + threadIdx.x;
    if (i < e) atomicAdd(&cnt[dst[i]], 1);
}

__global__ void scan_kernel(const int* __restrict__ cnt, int* __restrict__ off, int n) {
    __shared__ int sums[1024];
    int tid = threadIdx.x;
    int chunk = (n + 1023) >> 10;
    int b0 = tid * chunk;
    int b1 = min(b0 + chunk, n);
    int s = 0;
    for (int i = b0; i < b1; ++i) s += cnt[i];
    sums[tid] = s;
    __syncthreads();
    for (int d = 1; d < 1024; d <<= 1) {
        int v = (tid >= d) ? sums[tid - d] : 0;
        __syncthreads();
        sums[tid] += v;
        __syncthreads();
    }
    int pre = (tid == 0) ? 0 : sums[tid - 1];
    for (int i = b0; i < b1; ++i) { off[i] = pre; pre += cnt[i]; }
    if (tid == 1023) off[n] = pre;
}

__global__ void scatter_kernel(const int* __restrict__ src, const int* __restrict__ dst,
                               const int* __restrict__ off, int* __restrict__ cur,
                               int* __restrict__ csr, int e) {
    int i = blockIdx.x * blockDim.x + threadIdx.x;
    if (i < e) {
        int d = dst[i];
        int p = atomicAdd(&cur[d], 1);
        csr[off[d] + p] = src[i];
    }
}

__global__ void scaler_kernel(const int* __restrict__ cnt, float* __restrict__ amp,
                              float* __restrict__ att, float avg_log, int n) {
    int i = blockIdx.x * blockDim.x + threadIdx.x;
    if (i < n) {
        float deg = fmaxf((float)cnt[i], 1.0f);
        float ld = logf(deg + 1.0f);
        amp[i] = ld / avg_log;
        att[i] = avg_log / ld;
    }
}

// ---------------- weight / input prep ----------------

__global__ void xprep_kernel(const float* __restrict__ x, u16* __restrict__ xbuf,
                             u16* __restrict__ cat) {
    int i = blockIdx.x * 256 + threadIdx.x;
    if (i < NN * F) {
        u16 h = f2bf(x[i]);
        xbuf[i] = h;
        cat[(size_t)(i >> 7) * CATW + (i & 127)] = h;
    }
}

__global__ void wpreT_kernel(const float* __restrict__ W_pre, u16* __restrict__ dst) {
    int l = blockIdx.y;
    int i = blockIdx.x * 256 + threadIdx.x;
    if (i < 256 * 128) {
        int c = i >> 7, k = i & 127;
        int si = (c < 128) ? (k * 128 + c) : ((k + 128) * 128 + (c - 128));
        dst[l * 32768 + i] = f2bf(W_pre[l * 32768 + si]);
    }
}

__global__ void wlinT_kernel(const float* __restrict__ W_lin, u16* __restrict__ dst) {
    int l = blockIdx.y;
    int i = blockIdx.x * 256 + threadIdx.x;
    if (i < 128 * 128) {
        int c = i >> 7, k = i & 127;
        dst[l * 16384 + i] = f2bf(W_lin[l * 16384 + k * 128 + c]);
    }
}

__global__ void wpost_kernel(const float* __restrict__ W_post, u16* __restrict__ dst) {
    int i = blockIdx.x * 256 + threadIdx.x;
    if (i < 3 * 2048 * 128) dst[i] = f2bf(W_post[i]);
}

__global__ void bias_kernel(const float* __restrict__ b_pre, const float* __restrict__ b_post,
                            const float* __restrict__ b_lin, const float* __restrict__ W_lin,
                            float* __restrict__ biaspre, float* __restrict__ bcomb) {
    int l = blockIdx.x, t = threadIdx.x;
    if (t < 128) {
        float s = b_lin[l * 128 + t];
        for (int c = 0; c < 128; ++c) s += b_post[l * 128 + c] * W_lin[l * 16384 + c * 128 + t];
        bcomb[l * 128 + t] = s;
        biaspre[l * 256 + t] = b_pre[l * 128 + t];
    } else {
        biaspre[l * 256 + t] = 0.f;
    }
}

// BtK[l][cb][192][768]: row rho = g*64+jj -> out col j = cb*64+jj, group g
__global__ void brepack_kernel(const u16* __restrict__ Btcomb, u16* __restrict__ out) {
    int l = blockIdx.y;
    int i = blockIdx.x * 256 + threadIdx.x;   // 384*768
    if (i >= 384 * 768) return;
    int rho = i / 768, k = i % 768;
    int cb = rho / 192, rr = rho % 192;
    int g = rr / 64, jj = rr % 64;
    int j = cb * 64 + jj;
    const u16* B = Btcomb + (size_t)l * 262144;
    u16 v;
    if (k < 128) v = (g == 0) ? B[j * 2048 + k] : (u16)0;
    else         v = B[j * 2048 + 128 + g * 640 + (k - 128)];
    out[(size_t)l * 294912 + i] = v;
}

// ---------------- aggregation: one wave per node, 4-edge unroll ----------------

__global__ void agg_kernel(const u16* __restrict__ preout, const int* __restrict__ off,
                           const int* __restrict__ csr, u16* __restrict__ cat) {
    int gid = blockIdx.x * blockDim.x + threadIdx.x;
    int node = gid >> 6, lane = threadIdx.x & 63;
    if (node >= NN) return;
    int o0 = off[node], o1 = off[node + 1];
    const u32* bp = (const u32*)preout;           // row = 128 uints [c(64)|b(64)]
    float s0 = 0, s1 = 0, q0 = 0, q1 = 0;
    float mn0 = 1e30f, mn1 = 1e30f, mx0 = -1e30f, mx1 = -1e30f;
    int j = o0;
    for (; j + 4 <= o1; j += 4) {
        int i0 = csr[j], i1 = csr[j + 1], i2 = csr[j + 2], i3 = csr[j + 3];
        u32 u0 = bp[(size_t)i0 * 128 + 64 + lane];
        u32 u1 = bp[(size_t)i1 * 128 + 64 + lane];
        u32 u2 = bp[(size_t)i2 * 128 + 64 + lane];
        u32 u3 = bp[(size_t)i3 * 128 + 64 + lane];
        float v;
        v = bflo(u0); s0 += v; q0 = fmaf(v, v, q0); mn0 = fminf(mn0, v); mx0 = fmaxf(mx0, v);
        v = bfhi(u0); s1 += v; q1 = fmaf(v, v, q1); mn1 = fminf(mn1, v); mx1 = fmaxf(mx1, v);
        v = bflo(u1); s0 += v; q0 = fmaf(v, v, q0); mn0 = fminf(mn0, v); mx0 = fmaxf(mx0, v);
        v = bfhi(u1); s1 += v; q1 = fmaf(v, v, q1); mn1 = fminf(mn1, v); mx1 = fmaxf(mx1, v);
        v = bflo(u2); s0 += v; q0 = fmaf(v, v, q0); mn0 = fminf(mn0, v); mx0 = fmaxf(mx0, v);
        v = bfhi(u2); s1 += v; q1 = fmaf(v, v, q1); mn1 = fminf(mn1, v); mx1 = fmaxf(mx1, v);
        v = bflo(u3); s0 += v; q0 = fmaf(v, v, q0); mn0 = fminf(mn0, v); mx0 = fmaxf(mx0, v);
        v = bfhi(u3); s1 += v; q1 = fmaf(v, v, q1); mn1 = fminf(mn1, v); mx1 = fmaxf(mx1, v);
    }
    for (; j < o1; ++j) {
        u32 u = bp[(size_t)csr[j] * 128 + 64 + lane];
        float v;
        v = bflo(u); s0 += v; q0 = fmaf(v, v, q0); mn0 = fminf(mn0, v); mx0 = fmaxf(mx0, v);
        v = bfhi(u); s1 += v; q1 = fmaf(v, v, q1); mn1 = fminf(mn1, v); mx1 = fmaxf(mx1, v);
    }
    int degi = o1 - o0;
    float mean0, mean1, sum0, sum1, std0, std1, lo0, lo1, hi0, hi1;
    if (degi == 0) {
        sum0 = sum1 = 0.f; mean0 = mean1 = 0.f;
        std0 = std1 = sqrtf(1e-5f);
        lo0 = lo1 = hi0 = hi1 = 0.f;
    } else {
        u32 uc = bp[(size_t)node * 128 + lane];
        float c0 = bflo(uc), c1 = bfhi(uc), dg = (float)degi;
        sum0 = dg * c0 + s0; mean0 = sum0 / dg;
        sum1 = dg * c1 + s1; mean1 = sum1 / dg;
        float msq0 = c0 * c0 + (2.f * c0 * s0 + q0) / dg;
        float msq1 = c1 * c1 + (2.f * c1 * s1 + q1) / dg;
        std0 = sqrtf(fmaxf(msq0 - mean0 * mean0, 0.f) + 1e-5f);
        std1 = sqrtf(fmaxf(msq1 - mean1 * mean1, 0.f) + 1e-5f);
        lo0 = c0 + mn0; lo1 = c1 + mn1; hi0 = c0 + mx0; hi1 = c1 + mx1;
    }
    u32* cr = (u32*)cat + (size_t)node * (CATW / 2) + 64 + lane;
    float f0[5] = {mean0, sum0, std0, lo0, hi0};
    float f1[5] = {mean1, sum1, std1, lo1, hi1};
#pragma unroll
    for (int a = 0; a < 5; ++a)
        cr[a * 64] = (u32)f2bf(f0[a]) | ((u32)f2bf(f1[a]) << 16);
}

// ---------------- generic bf16 MFMA GEMM (pre_nn + weight-product) ----------------

template <bool BIAS>
__global__ __launch_bounds__(256) void mfma_gemm(
    const u16* __restrict__ A, int lda,
    const u16* __restrict__ Bt, int K,
    const float* __restrict__ bias,
    u16* __restrict__ C, int ldc, int Mreal) {
    __shared__ u16 As[64 * 32];
    __shared__ u16 Bs[128 * 32];
    int tid = threadIdx.x;
    int w = tid >> 6, lane = tid & 63;
    int row0 = blockIdx.x * 64, col0 = blockIdx.y * 128;

    int arow = tid >> 2, asl = tid & 3;
    const u16* agp = A + (size_t)(row0 + arow) * lda + ((asl ^ ((arow >> 1) & 3)) << 3);
    u16* alds = As + w * 512;
    int br0 = tid >> 2;
    int br1 = 64 + (tid >> 2);
    const u16* bgp0 = Bt + (size_t)(col0 + br0) * K + (((tid & 3) ^ ((br0 >> 1) & 3)) << 3);
    const u16* bgp1 = Bt + (size_t)(col0 + br1) * K + (((tid & 3) ^ ((br1 >> 1) & 3)) << 3);
    u16* blds0 = Bs + w * 512;
    u16* blds1 = Bs + 2048 + w * 512;

    f32x4 acc[2][4];
#pragma unroll
    for (int m = 0; m < 2; ++m)
#pragma unroll
        for (int n = 0; n < 4; ++n) acc[m][n] = (f32x4){0.f, 0.f, 0.f, 0.f};

    int s = lane >> 4, r = lane & 15;
    int wr = (w >> 1) * 32, wc = (w & 1) * 64;

    for (int k0 = 0; k0 < K; k0 += 32) {
        gload16(agp + k0, alds);
        gload16(bgp0 + k0, blds0);
        gload16(bgp1 + k0, blds1);
        __syncthreads();
        bf16x8 a[2], b[4];
#pragma unroll
        for (int m = 0; m < 2; ++m) {
            int row = wr + m * 16 + r;
            a[m] = *(const bf16x8*)&As[row * 32 + ((s ^ ((row >> 1) & 3)) << 3)];
        }
#pragma unroll
        for (int n = 0; n < 4; ++n) {
            int col = wc + n * 16 + r;
            b[n] = *(const bf16x8*)&Bs[col * 32 + ((s ^ ((col >> 1) & 3)) << 3)];
        }
#pragma unroll
        for (int m = 0; m < 2; ++m)
#pragma unroll
            for (int n = 0; n < 4; ++n)
                acc[m][n] = __builtin_amdgcn_mfma_f32_16x16x32_bf16(a[m], b[n], acc[m][n], 0, 0, 0);
        __syncthreads();
    }

#pragma unroll
    for (int m = 0; m < 2; ++m) {
#pragma unroll
        for (int n = 0; n < 4; ++n) {
            int gcol = col0 + wc + n * 16 + r;
            float bs = BIAS ? bias[gcol] : 0.f;
#pragma unroll
            for (int j = 0; j < 4; ++j) {
                int grow = row0 + wr + m * 16 + s * 4 + j;
                if (grow < Mreal)
                    C[(size_t)grow * ldc + gcol] = f2bf(acc[m][n][j] + bs);
            }
        }
    }
}

// ---------------- fused comb GEMM ----------------

__global__ __launch_bounds__(256) void comb_gemm(
    const u16* __restrict__ A,
    const u16* __restrict__ BtK,          // layer base: [2][192][768]
    const float* __restrict__ bias,
    const float* __restrict__ amp, const float* __restrict__ att,
    u16* __restrict__ xout,
    u16* __restrict__ catout) {
    __shared__ u16 S[256 * 64];           // 32 KB: rows 0..63 A, 64..255 B
    int tid = threadIdx.x;
    int row0 = blockIdx.x * 64;
    int cb = blockIdx.y;
    const u16* Bt = BtK + (size_t)cb * 192 * 768;

    int srow = tid >> 3, slot = tid & 7;
    const u16* gp[8];
#pragma unroll
    for (int t = 0; t < 8; ++t) {
        int row = t * 32 + srow;
        int koff = (slot ^ (row & 7)) << 3;
        if (row < 64) gp[t] = A + (size_t)(row0 + row) * 768 + koff;
        else          gp[t] = Bt + (size_t)(row - 64) * 768 + koff;
    }

    int lane = tid & 63, w = tid >> 6;
    int wr = (w >> 1) * 32, wwc = (w & 1) * 32;
    int r = lane & 15, s = lane >> 4;

    f32x4 acc[2][3][2];
#pragma unroll
    for (int m = 0; m < 2; ++m)
#pragma unroll
        for (int g = 0; g < 3; ++g)
#pragma unroll
            for (int n = 0; n < 2; ++n) acc[m][g][n] = (f32x4){0.f, 0.f, 0.f, 0.f};

    for (int k0 = 0; k0 < 768; k0 += 64) {
#pragma unroll
        for (int t = 0; t < 8; ++t)
            gload16(gp[t] + k0, S + ((size_t)(t * 256 + tid) << 3));
        __syncthreads();
#pragma unroll
        for (int kk = 0; kk < 2; ++kk) {
            int sl = kk * 4 + s;
            bf16x8 a[2];
#pragma unroll
            for (int m = 0; m < 2; ++m) {
                int row = wr + m * 16 + r;
                a[m] = *(const bf16x8*)&S[row * 64 + ((sl ^ (row & 7)) << 3)];
            }
            bf16x8 b[3][2];
#pragma unroll
            for (int g = 0; g < 3; ++g)
#pragma unroll
                for (int n = 0; n < 2; ++n) {
                    int brow = g * 64 + wwc + n * 16 + r;
                    b[g][n] = *(const bf16x8*)&S[4096 + brow * 64 + ((sl ^ (brow & 7)) << 3)];
                }
#pragma unroll
            for (int m = 0; m < 2; ++m)
#pragma unroll
                for (int g = 0; g < 3; ++g)
#pragma unroll
                    for (int n = 0; n < 2; ++n)
                        acc[m][g][n] = __builtin_amdgcn_mfma_f32_16x16x32_bf16(a[m], b[g][n], acc[m][g][n], 0, 0, 0);
        }
        __syncthreads();
    }

    int gcb = cb * 64 + wwc;
#pragma unroll
    for (int m = 0; m < 2; ++m) {
#pragma unroll
        for (int j = 0; j < 4; ++j) {
            int grow = row0 + wr + m * 16 + s * 4 + j;
            if (grow < NN) {
                float am = amp[grow], at = att[grow];
#pragma unroll
                for (int n = 0; n < 2; ++n) {
                    int gcol = gcb + n * 16 + r;
                    float v = acc[m][0][n][j] + am * acc[m][1][n][j] + at * acc[m][2][n][j] + bias[gcol];
                    v = fmaxf(v, 0.f);
                    u16 h = f2bf(v);
                    xout[(size_t)grow * F + gcol] = h;
                    catout[(size_t)grow * CATW + gcol] = h;
                }
            }
        }
    }
}

// ---------------- final output ----------------

__global__ void out_kernel(const u16* __restrict__ x, const float* __restrict__ Wout,
                           const float* __restrict__ bout, float* __restrict__ y) {
    int gid = blockIdx.x * blockDim.x + threadIdx.x;
    int wid = gid >> 6, lane = threadIdx.x & 63;
    if (wid >= NN) return;
    u32 u = *(const u32*)&x[(size_t)wid * F + 2 * lane];
    float v = bflo(u) * Wout[2 * lane] + bfhi(u) * Wout[2 * lane + 1];
#pragma unroll
    for (int o = 32; o > 0; o >>= 1) v += __shfl_down(v, o, 64);
    if (lane == 0) y[wid] = v + bout[0];
}

// ---------------- host ----------------

extern "C" void kernel_launch(void* const* d_in, const int* in_sizes, int n_in,
                              void* d_out, int out_size, void* d_ws, size_t ws_size,
                              hipStream_t stream) {
    const float* x_in   = (const float*)d_in[0];
    const int*   ei     = (const int*)d_in[1];
    const float* W_pre  = (const float*)d_in[2];
    const float* b_pre  = (const float*)d_in[3];
    const float* W_post = (const float*)d_in[4];
    const float* b_post = (const float*)d_in[5];
    const float* W_lin  = (const float*)d_in[6];
    const float* b_lin  = (const float*)d_in[7];
    const float* W_out  = (const float*)d_in[8];
    const float* b_out  = (const float*)d_in[9];

    const int* src = ei;
    const int* dst = ei + NE;

    double sl = 0.0;
    for (int i = 0; i < 33; ++i) sl += log((double)(i + 1));
    float avg_log = (float)(sl / 33.0);

    char* ws = (char*)d_ws;
    size_t p = 0;
    auto alloc = [&](size_t bytes) { void* r = ws + p; p += (bytes + 255) & ~(size_t)255; return r; };
    u16*   cat     = (u16*)alloc((size_t)MPAD * CATW * 2);
    u16*   xbuf    = (u16*)alloc((size_t)MPAD * F * 2);
    u16*   preout  = (u16*)alloc((size_t)MPAD * 256 * 2);
    u16*   WpreT   = (u16*)alloc((size_t)3 * 256 * 128 * 2);
    u16*   Wpostb  = (u16*)alloc((size_t)3 * 2048 * 128 * 2);
    u16*   WlinT   = (u16*)alloc((size_t)3 * 128 * 128 * 2);
    u16*   Btcomb  = (u16*)alloc((size_t)3 * 128 * 2048 * 2);
    u16*   BtK     = (u16*)alloc((size_t)3 * 384 * 768 * 2);
    float* biaspre = (float*)alloc((size_t)3 * 256 * 4);
    float* bcomb   = (float*)alloc((size_t)3 * 128 * 4);
    float* amp     = (float*)alloc((size_t)NN * 4);
    float* att     = (float*)alloc((size_t)NN * 4);
    int*   cnt     = (int*)alloc((size_t)NN * 4);
    int*   offs    = (int*)alloc((size_t)(NN + 1) * 4);
    int*   cur     = (int*)alloc((size_t)NN * 4);
    int*   csr     = (int*)alloc((size_t)NE * 4);
    (void)ws_size;

    xprep_kernel<<<(NN * F + 255) / 256, 256, 0, stream>>>(x_in, xbuf, cat);
    wpreT_kernel<<<dim3(128, 3), 256, 0, stream>>>(W_pre, WpreT);
    wlinT_kernel<<<dim3(64, 3), 256, 0, stream>>>(W_lin, WlinT);
    wpost_kernel<<<3072, 256, 0, stream>>>(W_post, Wpostb);
    bias_kernel<<<3, 256, 0, stream>>>(b_pre, b_post, b_lin, W_lin, biaspre, bcomb);

    zero_ints_kernel<<<(NN + 255) / 256, 256, 0, stream>>>(cnt, cur, NN);
    hist_kernel<<<(NE + 255) / 256, 256, 0, stream>>>(dst, cnt, NE);
    scan_kernel<<<1, 1024, 0, stream>>>(cnt, offs, NN);
    scaler_kernel<<<(NN + 255) / 256, 256, 0, stream>>>(cnt, amp, att, avg_log, NN);
    scatter_kernel<<<(NE + 255) / 256, 256, 0, stream>>>(src, dst, offs, cur, csr, NE);

    for (int l = 0; l < NLAYER; ++l) {
        mfma_gemm<false><<<dim3(2, 16), 256, 0, stream>>>(
            WlinT + (size_t)l * 16384, 128, Wpostb + (size_t)l * 262144, 128,
            nullptr, Btcomb + (size_t)l * 262144, 2048, 128);
    }
    brepack_kernel<<<dim3(1152, 3), 256, 0, stream>>>(Btcomb, BtK);

    for (int l = 0; l < NLAYER; ++l) {
        mfma_gemm<true><<<dim3(313, 2), 256, 0, stream>>>(
            xbuf, F, WpreT + (size_t)l * 32768, 128,
            biaspre + (size_t)l * 256, preout, 256, NN);
        agg_kernel<<<5000, 256, 0, stream>>>(preout, offs, csr, cat);
        comb_gemm<<<dim3(313, 2), 256, 0, stream>>>(
            cat, BtK + (size_t)l * 294912, bcomb + (size_t)l * 128,
            amp, att, xbuf, cat);
    }

    out_kernel<<<5000, 256, 0, stream>>>(xbuf, W_out, b_out, (float*)d_out);
}